// Round 10
// baseline (210.059 us; speedup 1.0000x reference)
//
#include <hip/hip_runtime.h>
#include <math.h>

// Problem constants: n=2, c=256, t=2, h=64, w=64; HB=WB=16, bn_h=bn_w=4;
// NHEAD=8, d=32. Stage1: L1=32 tokens x B1=512 batch. Stage2: L2=512 x B2=32.
// Token id m1 = l1*512 + b1, l1=(t*4+bh)*4+bw, b1=n*256+i*16+j.
// Token id m2 = l2*32 + b2,  l2=t*256+i*16+j,  b2=n*16+bh*4+bw.
// R20 = R19 with the attn2_mega correctness fix: the cross-lane li
// (softmax denominator) reduction via __shfl_xor over the 16-lane group
// was missing -- each lane only held its own 2 key-columns' partial sum.
// Restored (identical to attn2_mfma's end-of-loop reduction). All other
// code unchanged from R19 (R13 pack + R13 attn1_giga + fused attn2+out-proj).

#define SCALE_D32 0.17677669529663687f       // 1/sqrt(32)
#define EXP2_SCALE 0.25508680987930193f      // SCALE_D32 * log2(e)
#define GLOBAL_AS __attribute__((address_space(1)))
#define LDS_AS __attribute__((address_space(3)))

typedef short short8 __attribute__((ext_vector_type(8)));   // 8 bf16 = 16B
typedef short short4v __attribute__((ext_vector_type(4)));  // 4 bf16 = 8B
typedef short short2v __attribute__((ext_vector_type(2)));  // 2 bf16 = 4B
typedef float floatx4 __attribute__((ext_vector_type(4)));  // MFMA C/D frag

__device__ __forceinline__ short f2bf(float f) {
  union { float f; unsigned u; } x;
  x.f = f;
  unsigned r = x.u + 0x7fffu + ((x.u >> 16) & 1u);  // RNE
  return (short)(r >> 16);
}
__device__ __forceinline__ float bf2f(short s) {
  union { unsigned u; float f; } x;
  x.u = ((unsigned)(unsigned short)s) << 16;
  return x.f;
}

// physical index into a swizzled [R][256] bf16 tile (16B chunks XOR-swizzled
// within each 128B block by row&7; matches gemm_tri's As layout)
__device__ __forceinline__ int o1s_phys(int q, int ch) {
  return q * 256 + (ch & ~63) + ((((ch >> 3) & 7) ^ (q & 7)) << 3) + (ch & 7);
}

// stage one 256x64 bf16 W k-block into LDS, swizzle c^(row&7), 16B DMA
// (256-thread version, used by attn1_giga)
__device__ __forceinline__ void stage_w(short* Wsl, const short* Wg, int kb,
                                        int wave, int lane, int rsub, int csub) {
#pragma unroll
  for (int j = 0; j < 8; ++j) {
    int r0 = (wave * 8 + j) * 8;
    int row = r0 + rsub;
    int c = csub ^ (row & 7);
    const short* gp = Wg + (long)row * 256 + kb * 64 + c * 8;
    short* lp = &Wsl[r0 * 64 + lane * 8];
    __builtin_amdgcn_global_load_lds((const GLOBAL_AS void*)gp,
                                     (LDS_AS void*)lp, 16, 0, 0);
  }
}

// same staging with 512 threads (4 chunks each) -- used by attn2_mega
__device__ __forceinline__ void stage_w512(short* Ws, const short* Wg,
                                           int kb, int tid) {
#pragma unroll
  for (int j = 0; j < 4; ++j) {
    int idx = j * 512 + tid;     // 0..2047 (16B chunks)
    int row = idx >> 3;          // 0..255
    int c = idx & 7;
    int cs = c ^ (row & 7);
    const short* gp = Wg + (long)row * 256 + kb * 64 + cs * 8;
    __builtin_amdgcn_global_load_lds((const GLOBAL_AS void*)gp,
                                     (LDS_AS void*)(Ws + idx * 8), 16, 0, 0);
  }
}

// stage a full 32x256 bf16 token tile (rows m1 = l1*512 + b1) into swizzled
// LDS: linear dest, pre-swizzled global source (within-128B-block chunk XOR)
__device__ __forceinline__ void stage_tile(short* dst, const short* Xg,
                                           int b1, int tid) {
#pragma unroll
  for (int p = 0; p < 4; ++p) {
    int idx = p * 256 + tid;       // 0..1023
    int row = idx >> 5;            // 0..31
    int ch = idx & 31;             // 16B chunk within row
    int chs = (ch & ~7) | ((ch & 7) ^ (row & 7));
    const short* gp = Xg + ((long)(row * 512 + b1)) * 256 + chs * 8;
    short* lp = dst + idx * 8;
    __builtin_amdgcn_global_load_lds((const GLOBAL_AS void*)gp,
                                     (LDS_AS void*)lp, 16, 0, 0);
  }
}

// ---- pack: [n,c,t,h,w] fp32 -> token-major [16384,256] bf16; + weight cvt --
// (R13 original)
__global__ __launch_bounds__(256) void pack_kernel(
    const float* __restrict__ q, const float* __restrict__ k,
    const float* __restrict__ v, const float* __restrict__ pos,
    short* __restrict__ Xp, short* __restrict__ Xq,
    short* __restrict__ Xk, short* __restrict__ Xv,
    const float* __restrict__ wl_in, const float* __restrict__ wl_out,
    const float* __restrict__ ws_in, const float* __restrict__ ws_out,
    short* __restrict__ wbf) {
  __shared__ float tP[64][65];
  __shared__ float tX[64][65];
  int b = blockIdx.x;
  int cb = b & 3;
  int h  = (b >> 2) & 63;
  int nt = b >> 8;
  int n = nt >> 1, t = nt & 1;
  int c0 = cb * 64;
  int bh = h >> 4, ii = h & 15;
  long inbase = (long)n * 2097152 + (long)t * 4096 + (long)h * 64;
  int tx = threadIdx.x & 63;
  int ty = threadIdx.x >> 6;  // 0..3

  for (int cc = ty; cc < 64; cc += 4) {
    long a = inbase + (long)(c0 + cc) * 8192 + tx;
    tP[cc][tx] = pos[a];
    tX[cc][tx] = q[a];
  }
  __syncthreads();
  for (int ww = ty; ww < 64; ww += 4) {
    int bw = ww >> 4, j = ww & 15;
    int m1 = (((t * 4 + bh) * 4 + bw) * 512) + n * 256 + ii * 16 + j;
    long o = (long)m1 * 256 + c0 + tx;
    float pv = tP[tx][ww];
    Xp[o] = f2bf(pv);
    Xq[o] = f2bf(tX[tx][ww] + pv);
  }
  __syncthreads();
  for (int cc = ty; cc < 64; cc += 4) {
    long a = inbase + (long)(c0 + cc) * 8192 + tx;
    tX[cc][tx] = k[a];
  }
  __syncthreads();
  for (int ww = ty; ww < 64; ww += 4) {
    int bw = ww >> 4, j = ww & 15;
    int m1 = (((t * 4 + bh) * 4 + bw) * 512) + n * 256 + ii * 16 + j;
    long o = (long)m1 * 256 + c0 + tx;
    Xk[o] = f2bf(tX[tx][ww] + tP[tx][ww]);
  }
  __syncthreads();
  for (int cc = ty; cc < 64; cc += 4) {
    long a = inbase + (long)(c0 + cc) * 8192 + tx;
    tX[cc][tx] = v[a];
  }
  __syncthreads();
  for (int ww = ty; ww < 64; ww += 4) {
    int bw = ww >> 4, j = ww & 15;
    int m1 = (((t * 4 + bh) * 4 + bw) * 512) + n * 256 + ii * 16 + j;
    long o = (long)m1 * 256 + c0 + tx;
    Xv[o] = f2bf(tX[tx][ww]);
  }
  // weight convert tail: 1024 blocks x 256 threads x 2 floats = 524288
  int idx = (blockIdx.x * 256 + threadIdx.x) * 2;
  const float* wp;
  if (idx < 196608) wp = wl_in + idx;
  else if (idx < 262144) wp = wl_out + (idx - 196608);
  else if (idx < 458752) wp = ws_in + (idx - 262144);
  else wp = ws_out + (idx - 458752);
  float2 wv = *(const float2*)wp;
  wbf[idx] = f2bf(wv.x);
  wbf[idx + 1] = f2bf(wv.y);
}

// ---- giga-fused stage-1 (R13 verbatim): in-proj + attn + out-proj + perm +
// pos + s2-in-proj. One block (4 waves) per b1. 80 KB -> 2 blk/CU.
__global__ __launch_bounds__(256) void attn1_giga(
    const short* __restrict__ Xq, const short* __restrict__ Xk,
    const short* __restrict__ Xv, const short* __restrict__ Xp,
    const short* __restrict__ Wlin, const float* __restrict__ bias_lin,
    const short* __restrict__ Wo, const float* __restrict__ bias_o,
    const short* __restrict__ Wsin, const float* __restrict__ bias_sin,
    short* __restrict__ Q2, short* __restrict__ K2, short* __restrict__ V2) {
  __shared__ short R1[32 * 256];   // 16 KB
  __shared__ short R2[32 * 256];   // 16 KB
  __shared__ short R3[32 * 256];   // 16 KB
  __shared__ short R4[256 * 64];   // 32 KB (Ws; or Vt+Pw during attn)
  int b1 = blockIdx.x;
  int tid = threadIdx.x;
  int wave = tid >> 6, lane = tid & 63;
  int l15 = lane & 15, quad = lane >> 4;
  int x7 = l15 & 7;
  int rsub = lane >> 3;
  int csub = lane & 7;

  floatx4 acc[2][4];

  // ======== phase A: Q1/K1/V1 = Xz @ wl_z^T + b_z, in place ========
#pragma unroll 1
  for (int z = 0; z < 3; ++z) {
    short* Rz = (z == 0) ? R1 : ((z == 1) ? R2 : R3);
    const short* Xg = (z == 0) ? Xq : ((z == 1) ? Xk : Xv);
    const short* Wz = Wlin + z * 65536;
    stage_tile(Rz, Xg, b1, tid);
#pragma unroll
    for (int mt = 0; mt < 2; ++mt)
#pragma unroll
      for (int nt = 0; nt < 4; ++nt) acc[mt][nt] = (floatx4)(0.f);
    for (int kb = 0; kb < 4; ++kb) {
      __syncthreads();   // prior Ws reads done; kb=0: tile DMA drained
      stage_w(R4, Wz, kb, wave, lane, rsub, csub);
      __syncthreads();
#pragma unroll
      for (int ks = 0; ks < 2; ++ks) {
        int pc = (ks * 4 + quad) ^ x7;
        short8 af[2], bfr[4];
#pragma unroll
        for (int mt = 0; mt < 2; ++mt)
          af[mt] = *(const short8*)&Rz[(mt * 16 + l15) * 256 + kb * 64 + pc * 8];
#pragma unroll
        for (int nt = 0; nt < 4; ++nt)
          bfr[nt] = *(const short8*)&R4[(wave * 64 + nt * 16 + l15) * 64 + pc * 8];
#pragma unroll
        for (int mt = 0; mt < 2; ++mt)
#pragma unroll
          for (int nt = 0; nt < 4; ++nt)
            acc[mt][nt] = __builtin_amdgcn_mfma_f32_16x16x32_bf16(
                af[mt], bfr[nt], acc[mt][nt], 0, 0, 0);
      }
    }
    __syncthreads();  // all waves done reading Rz before overwrite
    float bz[4];
#pragma unroll
    for (int nt = 0; nt < 4; ++nt)
      bz[nt] = bias_lin[z * 256 + wave * 64 + nt * 16 + l15];
#pragma unroll
    for (int mt = 0; mt < 2; ++mt)
#pragma unroll
      for (int r = 0; r < 4; ++r) {
        int row = mt * 16 + quad * 4 + r;
#pragma unroll
        for (int nt = 0; nt < 4; ++nt) {
          int col = wave * 64 + nt * 16 + l15;
          Rz[o1s_phys(row, col)] = f2bf(acc[mt][nt][r] + bz[nt]);
        }
      }
  }
  __syncthreads();  // Q1/K1/V1 tiles visible to all waves

  // ======== phase B: attention (frags from swizzled LDS) ========
  short* Vtb = R4;           // [4][32][40] shorts = 5120
  short* Pwb = R4 + 5120;    // [4][32][40]
  int key = lane & 31;
  int dh = (lane >> 5) * 16;                 // 0 or 16
  int pc2 = 2 * (key & 15) + (key >> 4);     // pi2(key)

  floatx4 oacc[2][4];    // [h2][o00,o01,o10,o11]
  float lsum[2][2][4];   // [h2][li0/li1][r]

#pragma unroll
  for (int h2 = 0; h2 < 2; ++h2) {
    int hh = wave * 2 + h2;
    int cb0 = hh * 32 + quad * 8;
    short8 qf0 = *(const short8*)&R1[o1s_phys(l15, cb0)];
    short8 qf1 = *(const short8*)&R1[o1s_phys(l15 + 16, cb0)];
    short8 kf0 = *(const short8*)&R2[o1s_phys(l15, cb0)];
    short8 kf1 = *(const short8*)&R2[o1s_phys(l15 + 16, cb0)];
    // V^T for this head: Vt[d][pi2(key)]; lanes 0-31: d 0..15, 32-63: 16..31
    short8 v0 = *(const short8*)&R3[o1s_phys(key, hh * 32 + dh)];
    short8 v1 = *(const short8*)&R3[o1s_phys(key, hh * 32 + dh + 8)];
#pragma unroll
    for (int j = 0; j < 8; ++j) {
      Vtb[(wave * 32 + dh + j) * 40 + pc2] = v0[j];
      Vtb[(wave * 32 + dh + 8 + j) * 40 + pc2] = v1[j];
    }
    // S = Q K^T (4 tiles)
    floatx4 s00 = __builtin_amdgcn_mfma_f32_16x16x32_bf16(qf0, kf0, (floatx4)(0.f), 0, 0, 0);
    floatx4 s01 = __builtin_amdgcn_mfma_f32_16x16x32_bf16(qf0, kf1, (floatx4)(0.f), 0, 0, 0);
    floatx4 s10 = __builtin_amdgcn_mfma_f32_16x16x32_bf16(qf1, kf0, (floatx4)(0.f), 0, 0, 0);
    floatx4 s11 = __builtin_amdgcn_mfma_f32_16x16x32_bf16(qf1, kf1, (floatx4)(0.f), 0, 0, 0);
    // no-max softmax; P[q][pi2(k)]: key tiles j=0,1 -> cols 2*l15, 2*l15+1
    float li0[4], li1[4];
#pragma unroll
    for (int r = 0; r < 4; ++r) {
      float p00 = __builtin_amdgcn_exp2f(s00[r] * EXP2_SCALE);
      float p01 = __builtin_amdgcn_exp2f(s01[r] * EXP2_SCALE);
      float p10 = __builtin_amdgcn_exp2f(s10[r] * EXP2_SCALE);
      float p11 = __builtin_amdgcn_exp2f(s11[r] * EXP2_SCALE);
      li0[r] = p00 + p01;
      li1[r] = p10 + p11;
      short2v pa, pb;
      pa.x = f2bf(p00); pa.y = f2bf(p01);
      pb.x = f2bf(p10); pb.y = f2bf(p11);
      *(short2v*)&Pwb[(wave * 32 + quad * 4 + r) * 40 + 2 * l15] = pa;
      *(short2v*)&Pwb[(wave * 32 + 16 + quad * 4 + r) * 40 + 2 * l15] = pb;
    }
#pragma unroll
    for (int r = 0; r < 4; ++r) {
      li0[r] += __shfl_xor(li0[r], 1, 64);
      li0[r] += __shfl_xor(li0[r], 2, 64);
      li0[r] += __shfl_xor(li0[r], 4, 64);
      li0[r] += __shfl_xor(li0[r], 8, 64);
      li1[r] += __shfl_xor(li1[r], 1, 64);
      li1[r] += __shfl_xor(li1[r], 2, 64);
      li1[r] += __shfl_xor(li1[r], 4, 64);
      li1[r] += __shfl_xor(li1[r], 8, 64);
      lsum[h2][0][r] = li0[r];
      lsum[h2][1][r] = li1[r];
    }
    // PV: O[32q][32d] = P[32q][32k] V[32k][32d] (k pi2-ordered both sides)
    short8 pf0 = *(const short8*)&Pwb[(wave * 32 + l15) * 40 + quad * 8];
    short8 pf1 = *(const short8*)&Pwb[(wave * 32 + 16 + l15) * 40 + quad * 8];
    short8 vt0 = *(const short8*)&Vtb[(wave * 32 + l15) * 40 + quad * 8];
    short8 vt1 = *(const short8*)&Vtb[(wave * 32 + 16 + l15) * 40 + quad * 8];
    oacc[h2][0] = __builtin_amdgcn_mfma_f32_16x16x32_bf16(pf0, vt0, (floatx4)(0.f), 0, 0, 0);
    oacc[h2][1] = __builtin_amdgcn_mfma_f32_16x16x32_bf16(pf0, vt1, (floatx4)(0.f), 0, 0, 0);
    oacc[h2][2] = __builtin_amdgcn_mfma_f32_16x16x32_bf16(pf1, vt0, (floatx4)(0.f), 0, 0, 0);
    oacc[h2][3] = __builtin_amdgcn_mfma_f32_16x16x32_bf16(pf1, vt1, (floatx4)(0.f), 0, 0, 0);
  }

  __syncthreads();  // attn LDS reads done; R4/R1 safe to overwrite

  // ---- issue Wo kb0 stage (into R4, overlays dead Vt/Pw), then spill ----
  stage_w(R4, Wo, 0, wave, lane, rsub, csub);
#pragma unroll
  for (int h2 = 0; h2 < 2; ++h2) {
    int hh = wave * 2 + h2;
    int cA = hh * 32 + l15;
    int cB = cA + 16;
#pragma unroll
    for (int r = 0; r < 4; ++r) {
      float inv0 = 1.f / lsum[h2][0][r];
      float inv1 = 1.f / lsum[h2][1][r];
      int qa = quad * 4 + r, qb = 16 + quad * 4 + r;
      R1[o1s_phys(qa, cA)] = f2bf(oacc[h2][0][r] * inv0);
      R1[o1s_phys(qa, cB)] = f2bf(oacc[h2][1][r] * inv0);
      R1[o1s_phys(qb, cA)] = f2bf(oacc[h2][2][r] * inv1);
      R1[o1s_phys(qb, cB)] = f2bf(oacc[h2][3][r] * inv1);
    }
  }
  __syncthreads();  // Wo kb0 staged + O1s spill visible

  // ======== phase C: C1 = O1s @ Wo^T ========
#pragma unroll
  for (int mt = 0; mt < 2; ++mt)
#pragma unroll
    for (int nt = 0; nt < 4; ++nt) acc[mt][nt] = (floatx4)(0.f);
  for (int kb = 0; kb < 4; ++kb) {
    if (kb) {
      __syncthreads();
      stage_w(R4, Wo, kb, wave, lane, rsub, csub);
      __syncthreads();
    }
#pragma unroll
    for (int ks = 0; ks < 2; ++ks) {
      int pc = (ks * 4 + quad) ^ x7;
      short8 af[2], bfr[4];
#pragma unroll
      for (int mt = 0; mt < 2; ++mt)
        af[mt] = *(const short8*)&R1[(mt * 16 + l15) * 256 + kb * 64 + pc * 8];
#pragma unroll
      for (int nt = 0; nt < 4; ++nt)
        bfr[nt] = *(const short8*)&R4[(wave * 64 + nt * 16 + l15) * 64 + pc * 8];
#pragma unroll
      for (int mt = 0; mt < 2; ++mt)
#pragma unroll
        for (int nt = 0; nt < 4; ++nt)
          acc[mt][nt] = __builtin_amdgcn_mfma_f32_16x16x32_bf16(
              af[mt], bfr[nt], acc[mt][nt], 0, 0, 0);
    }
  }

  __syncthreads();
  // ---- X2s (=C1+b+pos) -> R2, Vins (=C1+b) -> R3, both swizzled ----
  {
    float bvo[4];
#pragma unroll
    for (int nt = 0; nt < 4; ++nt) bvo[nt] = bias_o[wave * 64 + nt * 16 + l15];
#pragma unroll
    for (int mt = 0; mt < 2; ++mt) {
#pragma unroll
      for (int r = 0; r < 4; ++r) {
        int qrow = mt * 16 + quad * 4 + r;
        long pbase = ((long)qrow * 512 + b1) * 256;
#pragma unroll
        for (int nt = 0; nt < 4; ++nt) {
          int col = wave * 64 + nt * 16 + l15;
          float val = acc[mt][nt][r] + bvo[nt];
          int ph = o1s_phys(qrow, col);
          R3[ph] = f2bf(val);
          R2[ph] = f2bf(val + bf2f(Xp[pbase + col]));  // X2s
        }
      }
    }
  }

  // ======== phase D: Q2/K2/V2 = {X2s,X2s,Vins} @ ws_{q,k,v}^T + b ========
  int nn = b1 >> 8, ii = (b1 >> 4) & 15, jj = b1 & 15;
#pragma unroll 1
  for (int z = 0; z < 3; ++z) {
    const short* Wz = Wsin + z * 65536;
    const short* Ab = (z < 2) ? R2 : R3;
    short* outz = (z == 0) ? Q2 : ((z == 1) ? K2 : V2);
    float bz[4];
#pragma unroll
    for (int nt = 0; nt < 4; ++nt)
      bz[nt] = bias_sin[z * 256 + wave * 64 + nt * 16 + l15];
#pragma unroll
    for (int mt = 0; mt < 2; ++mt)
#pragma unroll
      for (int nt = 0; nt < 4; ++nt) acc[mt][nt] = (floatx4)(0.f);
    for (int kb = 0; kb < 4; ++kb) {
      __syncthreads();  // z0/kb0: X2s/Vins visible; else prior Ws reads done
      stage_w(R4, Wz, kb, wave, lane, rsub, csub);
      __syncthreads();
#pragma unroll
      for (int ks = 0; ks < 2; ++ks) {
        int pc = (ks * 4 + quad) ^ x7;
        short8 af[2], bfr[4];
#pragma unroll
        for (int mt = 0; mt < 2; ++mt)
          af[mt] = *(const short8*)&Ab[(mt * 16 + l15) * 256 + kb * 64 + pc * 8];
#pragma unroll
        for (int nt = 0; nt < 4; ++nt)
          bfr[nt] = *(const short8*)&R4[(wave * 64 + nt * 16 + l15) * 64 + pc * 8];
#pragma unroll
        for (int mt = 0; mt < 2; ++mt)
#pragma unroll
          for (int nt = 0; nt < 4; ++nt)
            acc[mt][nt] = __builtin_amdgcn_mfma_f32_16x16x32_bf16(
                af[mt], bfr[nt], acc[mt][nt], 0, 0, 0);
      }
    }
    // epilogue: +bias, m1->m2 perm, store
#pragma unroll
    for (int mt = 0; mt < 2; ++mt) {
#pragma unroll
      for (int r = 0; r < 4; ++r) {
        int qrow = mt * 16 + quad * 4 + r;
        int t = qrow >> 4, bh = (qrow >> 2) & 3, bw = qrow & 3;
        int m2 = (t * 256 + ii * 16 + jj) * 32 + nn * 16 + bh * 4 + bw;
        long xbase = (long)m2 * 256;
#pragma unroll
        for (int nt = 0; nt < 4; ++nt) {
          int col = wave * 64 + nt * 16 + l15;
          outz[xbase + col] = f2bf(acc[mt][nt][r] + bz[nt]);
        }
      }
    }
  }
}

// ---- stage-2 attention + out-proj, fused (attn2_mega) ---------------------
// 256 blocks (qblk 0..7 x b2 0..31) x 512 threads; wave = head hh.
// Per block: 64 q-tokens, all heads. 16 chunks of 32 keys: K/V staged
// shared ([32][256], pre-swizzled source, linear gload_lds dest); per-wave
// attn1-style pi2 S/exp/P/PV, online li/O accumulation. Then O2 tile
// spilled swizzled to LDS, Y = O2 @ ws_out^T + bias written fp32 (m2 rows).
__global__ __launch_bounds__(512) void attn2_mega(
    const short* __restrict__ Q2, const short* __restrict__ K2,
    const short* __restrict__ V2, const short* __restrict__ Wout,
    const float* __restrict__ bias_out, float* __restrict__ Yf) {
  __shared__ union {
    struct {                    // attention phase: 94208 B
      short Ks[32 * 256];       // [key][c], 16B chunks XOR'd by key&7
      short Vs[32 * 256];       // same layout
      short Vt[8 * 32 * 40];    // per-head V^T [d][pi2(key)]
      short Pw[8 * 64 * 40];    // per-head P [q][pi2(key)]
    } a;
    struct {                    // out-proj phase: 65536 B
      short O2s[64 * 256];      // swizzled O2 tile
      short Ws[256 * 64];       // ws_out k-block, swizzled
    } g;
  } u;
  int bid = blockIdx.x;
  int qblk = bid >> 5, b2 = bid & 31;
  int tid = threadIdx.x;
  int hh = tid >> 6, lane = tid & 63;
  int l15 = lane & 15, quad = lane >> 4;
  int x7 = l15 & 7;

  // Q fragments: 4 q-tiles x (16 rows x 32 d), direct from global
  short8 qf[4];
#pragma unroll
  for (int qt = 0; qt < 4; ++qt) {
    long tok = (long)(qblk * 64 + qt * 16 + l15) * 32 + b2;
    qf[qt] = *(const short8*)(Q2 + tok * 256 + hh * 32 + quad * 8);
  }

  floatx4 Oa[4][2];
#pragma unroll
  for (int qt = 0; qt < 4; ++qt) {
    Oa[qt][0] = (floatx4)(0.f);
    Oa[qt][1] = (floatx4)(0.f);
  }
  float li[4][4];
#pragma unroll
  for (int qt = 0; qt < 4; ++qt)
#pragma unroll
    for (int r = 0; r < 4; ++r) li[qt][r] = 0.f;

  int key = lane & 31;
  int dh = (lane >> 5) * 16;                 // 0 or 16
  int pc2 = 2 * (key & 15) + (key >> 4);     // pi2(key)
  int lcv0 = hh * 4 + (dh >> 3);             // V chunk (d-half low 8)
  int pv0 = (lcv0 & ~7) | ((lcv0 & 7) ^ (key & 7));
  int lcv1 = lcv0 + 1;
  int pv1 = (lcv1 & ~7) | ((lcv1 & 7) ^ (key & 7));
  int lcK = hh * 4 + quad;
  int pk = (lcK & ~7) | ((lcK & 7) ^ x7);

  for (int kb = 0; kb < 16; ++kb) {
    if (kb) __syncthreads();   // all waves done with prior Ks/Vs
    // stage K/V [32 keys][256 c]: 1024 chunks each, 2 per thread
#pragma unroll
    for (int p = 0; p < 2; ++p) {
      int idx = p * 512 + tid;
      int row = idx >> 5, ch = idx & 31;
      int chs = (ch & ~7) | ((ch & 7) ^ (row & 7));
      long src = ((long)((kb * 32 + row) * 32 + b2)) * 256 + chs * 8;
      __builtin_amdgcn_global_load_lds((const GLOBAL_AS void*)(K2 + src),
                                       (LDS_AS void*)(u.a.Ks + idx * 8), 16, 0, 0);
      __builtin_amdgcn_global_load_lds((const GLOBAL_AS void*)(V2 + src),
                                       (LDS_AS void*)(u.a.Vs + idx * 8), 16, 0, 0);
    }
    __syncthreads();           // stage landed
    // V^T scatter for this head
    {
      short8 v0 = *(const short8*)&u.a.Vs[key * 256 + pv0 * 8];
      short8 v1 = *(const short8*)&u.a.Vs[key * 256 + pv1 * 8];
#pragma unroll
      for (int j = 0; j < 8; ++j) {
        u.a.Vt[(hh * 32 + dh + j) * 40 + pc2] = v0[j];
        u.a.Vt[(hh * 32 + dh + 8 + j) * 40 + pc2] = v1[j];
      }
    }
    short8 kf0 = *(const short8*)&u.a.Ks[l15 * 256 + pk * 8];
    short8 kf1 = *(const short8*)&u.a.Ks[(16 + l15) * 256 + pk * 8];
    // S = Q K^T, exp, pack P (pi2 cols 2*l15, 2*l15+1)
#pragma unroll
    for (int qt = 0; qt < 4; ++qt) {
      floatx4 s0 = __builtin_amdgcn_mfma_f32_16x16x32_bf16(qf[qt], kf0, (floatx4)(0.f), 0, 0, 0);
      floatx4 s1 = __builtin_amdgcn_mfma_f32_16x16x32_bf16(qf[qt], kf1, (floatx4)(0.f), 0, 0, 0);
#pragma unroll
      for (int r = 0; r < 4; ++r) {
        float p0 = __builtin_amdgcn_exp2f(s0[r] * EXP2_SCALE);
        float p1 = __builtin_amdgcn_exp2f(s1[r] * EXP2_SCALE);
        li[qt][r] += p0 + p1;
        short2v pa;
        pa.x = f2bf(p0); pa.y = f2bf(p1);
        *(short2v*)&u.a.Pw[(hh * 64 + qt * 16 + quad * 4 + r) * 40 + 2 * l15] = pa;
      }
    }
    // PV accumulate
    short8 vt0 = *(const short8*)&u.a.Vt[(hh * 32 + l15) * 40 + quad * 8];
    short8 vt1 = *(const short8*)&u.a.Vt[(hh * 32 + 16 + l15) * 40 + quad * 8];
#pragma unroll
    for (int qt = 0; qt < 4; ++qt) {
      short8 pf = *(const short8*)&u.a.Pw[(hh * 64 + qt * 16 + l15) * 40 + quad * 8];
      Oa[qt][0] = __builtin_amdgcn_mfma_f32_16x16x32_bf16(pf, vt0, Oa[qt][0], 0, 0, 0);
      Oa[qt][1] = __builtin_amdgcn_mfma_f32_16x16x32_bf16(pf, vt1, Oa[qt][1], 0, 0, 0);
    }
  }

  // ---- complete the softmax denominator: reduce li across the 16-lane
  // key-column group (was MISSING in R19 -- the R19 bug) ----
#pragma unroll
  for (int qt = 0; qt < 4; ++qt)
#pragma unroll
    for (int r = 0; r < 4; ++r) {
      float s = li[qt][r];
      s += __shfl_xor(s, 1, 64);
      s += __shfl_xor(s, 2, 64);
      s += __shfl_xor(s, 4, 64);
      s += __shfl_xor(s, 8, 64);
      li[qt][r] = s;
    }

  __syncthreads();  // all attn LDS reads done before overlay write

  // ---- normalize + spill O2 tile (bf16, swizzled) ----
#pragma unroll
  for (int qt = 0; qt < 4; ++qt)
#pragma unroll
    for (int r = 0; r < 4; ++r) {
      float inv = 1.f / li[qt][r];
      int q = qt * 16 + quad * 4 + r;
      u.g.O2s[o1s_phys(q, hh * 32 + l15)] = f2bf(Oa[qt][0][r] * inv);
      u.g.O2s[o1s_phys(q, hh * 32 + 16 + l15)] = f2bf(Oa[qt][1][r] * inv);
    }

  // ---- out-proj: Y[64][256] = O2s @ ws_out^T + bias (wave owns 32 cols) --
  floatx4 acc[4][2];
#pragma unroll
  for (int mt = 0; mt < 4; ++mt) {
    acc[mt][0] = (floatx4)(0.f);
    acc[mt][1] = (floatx4)(0.f);
  }
  for (int kb = 0; kb < 4; ++kb) {
    __syncthreads();  // kb0: spill visible; else prior Ws readers done
    stage_w512(u.g.Ws, Wout, kb, tid);
    __syncthreads();
#pragma unroll
    for (int ks = 0; ks < 2; ++ks) {
      int pc = (ks * 4 + quad) ^ x7;
      short8 af[4], bfr[2];
#pragma unroll
      for (int mt = 0; mt < 4; ++mt)
        af[mt] = *(const short8*)&u.g.O2s[(mt * 16 + l15) * 256 + kb * 64 + pc * 8];
#pragma unroll
      for (int nt = 0; nt < 2; ++nt)
        bfr[nt] = *(const short8*)&u.g.Ws[(hh * 32 + nt * 16 + l15) * 64 + pc * 8];
#pragma unroll
      for (int mt = 0; mt < 4; ++mt)
#pragma unroll
        for (int nt = 0; nt < 2; ++nt)
          acc[mt][nt] = __builtin_amdgcn_mfma_f32_16x16x32_bf16(
              af[mt], bfr[nt], acc[mt][nt], 0, 0, 0);
    }
  }
  float bo0 = bias_out[hh * 32 + l15];
  float bo1 = bias_out[hh * 32 + 16 + l15];
#pragma unroll
  for (int mt = 0; mt < 4; ++mt)
#pragma unroll
    for (int r = 0; r < 4; ++r) {
      long tok = (long)(qblk * 64 + mt * 16 + quad * 4 + r) * 32 + b2;
      Yf[tok * 256 + hh * 32 + l15] = acc[mt][0][r] + bo0;
      Yf[tok * 256 + hh * 32 + 16 + l15] = acc[mt][1][r] + bo1;
    }
}

// ---------------- unpack: [16384,256] fp32 (m2-order) -> out [n,c,t,h,w] ----
__global__ __launch_bounds__(256) void unpack_kernel(
    const float* __restrict__ Y, float* __restrict__ out) {
  __shared__ float tl[64][65];
  int b = blockIdx.x;
  int cb = b & 3;
  int h = (b >> 2) & 63;
  int nt = b >> 8;
  int n = nt >> 1, t = nt & 1;
  int c0 = cb * 64;
  int bh = h >> 4, ii = h & 15;
  int tx = threadIdx.x & 63;
  int ty = threadIdx.x >> 6;
  for (int ww = ty; ww < 64; ww += 4) {
    int bw = ww >> 4, j = ww & 15;
    int l2 = t * 256 + ii * 16 + j;
    int b2 = n * 16 + bh * 4 + bw;
    int m2 = l2 * 32 + b2;
    tl[tx][ww] = Y[(long)m2 * 256 + c0 + tx];
  }
  __syncthreads();
  long ob = (long)n * 2097152 + (long)t * 4096 + (long)h * 64 + tx;
  for (int cc = ty; cc < 64; cc += 4) {
    out[ob + (long)(c0 + cc) * 8192] = tl[cc][tx];
  }
}

extern "C" void kernel_launch(void* const* d_in, const int* in_sizes, int n_in,
                              void* d_out, int out_size, void* d_ws, size_t ws_size,
                              hipStream_t stream) {
  const float* q      = (const float*)d_in[0];
  const float* k      = (const float*)d_in[1];
  const float* v      = (const float*)d_in[2];
  const float* pos    = (const float*)d_in[3];
  const float* wl_in  = (const float*)d_in[4];
  const float* bl_in  = (const float*)d_in[5];
  const float* wl_out = (const float*)d_in[6];
  const float* bl_out = (const float*)d_in[7];
  const float* ws_in  = (const float*)d_in[8];
  const float* bs_in  = (const float*)d_in[9];
  const float* ws_out = (const float*)d_in[10];
  const float* bs_out = (const float*)d_in[11];
  float* out = (float*)d_out;
  char* wsb = (char*)d_ws;
  const size_t SLB = 16777216;  // 16 MB per slot (bf16 tensors use half)
  short* s0 = (short*)(wsb);            // Xp (8 MB)
  short* wbf = (short*)(wsb + SLB / 2); // bf16 weights (1 MB)
  short* s1 = (short*)(wsb + SLB);      // Xq
  short* s2 = (short*)(wsb + 2 * SLB);  // Xk -> Yfinal(fp32)
  short* s3 = (short*)(wsb + 3 * SLB);  // Xv
  short* s4 = (short*)(wsb + 4 * SLB);  // Q2
  short* s5 = (short*)(wsb + 5 * SLB);  // K2
  short* s6 = (short*)(wsb + 6 * SLB);  // V2

  pack_kernel<<<1024, 256, 0, stream>>>(q, k, v, pos, s0, s1, s2, s3,
                                        wl_in, wl_out, ws_in, ws_out, wbf);

  // giga-fused stage-1 (in-proj + attn + out-proj + perm + pos + s2 in-proj):
  // Q2 -> s4, K2 -> s5, V2 -> s6
  attn1_giga<<<512, 256, 0, stream>>>(s1, s2, s3, s0, wbf, bl_in,
                                      wbf + 196608, bl_out,
                                      wbf + 262144, bs_in, s4, s5, s6);

  // fused stage-2 attention + out-proj: Yfinal (fp32) -> s2
  attn2_mega<<<256, 512, 0, stream>>>(s4, s5, s6, wbf + 458752, bs_out,
                                      (float*)s2);

  unpack_kernel<<<1024, 256, 0, stream>>>((const float*)s2, out);
}

// Round 12
// 203.314 us; speedup vs baseline: 1.0332x; 1.0332x over previous
//
#include <hip/hip_runtime.h>
#include <math.h>

// Problem constants: n=2, c=256, t=2, h=64, w=64; HB=WB=16, bn_h=bn_w=4;
// NHEAD=8, d=32. Stage1: L1=32 tokens x B1=512 batch. Stage2: L2=512 x B2=32.
// Token id m1 = l1*512 + b1, l1=(t*4+bh)*4+bw, b1=n*256+i*16+j.
// Token id m2 = l2*32 + b2,  l2=t*256+i*16+j,  b2=n*16+bh*4+bw.
// R22 = resubmit of R21 (exact R13, best measured: 202.8 us). R21's bench
// failed on infra (container), not the kernel. Post-mortems of R14-R20:
// all seven structural variants (SW pipelining x2, direct-VGPR W reads,
// shared-W 512-thread, coalesced pack, tail fusion x2) were neutral or
// negative. The recurring mechanism: this chain is won by co-resident-block
// overlap (2+ blocks/CU), not by traffic/launch/barrier savings. R13 is the
// configuration that maximizes it at every stage: pack 4 blk/CU,
// attn1_giga 2 blk/CU, attn2_mfma 8 blk/CU, gemm_tri 8 blk/CU.

#define SCALE_D32 0.17677669529663687f       // 1/sqrt(32)
#define EXP2_SCALE 0.25508680987930193f      // SCALE_D32 * log2(e)
#define GLOBAL_AS __attribute__((address_space(1)))
#define LDS_AS __attribute__((address_space(3)))

typedef short short8 __attribute__((ext_vector_type(8)));   // 8 bf16 = 16B
typedef short short4v __attribute__((ext_vector_type(4)));  // 4 bf16 = 8B
typedef short short2v __attribute__((ext_vector_type(2)));  // 2 bf16 = 4B
typedef float floatx4 __attribute__((ext_vector_type(4)));  // MFMA C/D frag

__device__ __forceinline__ short f2bf(float f) {
  union { float f; unsigned u; } x;
  x.f = f;
  unsigned r = x.u + 0x7fffu + ((x.u >> 16) & 1u);  // RNE
  return (short)(r >> 16);
}
__device__ __forceinline__ float bf2f(short s) {
  union { unsigned u; float f; } x;
  x.u = ((unsigned)(unsigned short)s) << 16;
  return x.f;
}

// physical index into a swizzled [32][256] bf16 tile (16B chunks XOR-swizzled
// within each 128B block by row&7; matches gemm_tri's As layout)
__device__ __forceinline__ int o1s_phys(int q, int ch) {
  return q * 256 + (ch & ~63) + ((((ch >> 3) & 7) ^ (q & 7)) << 3) + (ch & 7);
}

// stage one 256x64 bf16 W k-block into LDS, gemm_tri swizzle, 16B DMA
__device__ __forceinline__ void stage_w(short* Wsl, const short* Wg, int kb,
                                        int wave, int lane, int rsub, int csub) {
#pragma unroll
  for (int j = 0; j < 8; ++j) {
    int r0 = (wave * 8 + j) * 8;
    int row = r0 + rsub;
    int c = csub ^ (row & 7);
    const short* gp = Wg + (long)row * 256 + kb * 64 + c * 8;
    short* lp = &Wsl[r0 * 64 + lane * 8];
    __builtin_amdgcn_global_load_lds((const GLOBAL_AS void*)gp,
                                     (LDS_AS void*)lp, 16, 0, 0);
  }
}

// stage a full 32x256 bf16 token tile (rows m1 = l1*512 + b1) into swizzled
// LDS: linear dest, pre-swizzled global source (within-128B-block chunk XOR)
__device__ __forceinline__ void stage_tile(short* dst, const short* Xg,
                                           int b1, int tid) {
#pragma unroll
  for (int p = 0; p < 4; ++p) {
    int idx = p * 256 + tid;       // 0..1023
    int row = idx >> 5;            // 0..31
    int ch = idx & 31;             // 16B chunk within row
    int chs = (ch & ~7) | ((ch & 7) ^ (row & 7));
    const short* gp = Xg + ((long)(row * 512 + b1)) * 256 + chs * 8;
    short* lp = dst + idx * 8;
    __builtin_amdgcn_global_load_lds((const GLOBAL_AS void*)gp,
                                     (LDS_AS void*)lp, 16, 0, 0);
  }
}

// ---- pack: [n,c,t,h,w] fp32 -> token-major [16384,256] bf16; + weight cvt --
__global__ __launch_bounds__(256) void pack_kernel(
    const float* __restrict__ q, const float* __restrict__ k,
    const float* __restrict__ v, const float* __restrict__ pos,
    short* __restrict__ Xp, short* __restrict__ Xq,
    short* __restrict__ Xk, short* __restrict__ Xv,
    const float* __restrict__ wl_in, const float* __restrict__ wl_out,
    const float* __restrict__ ws_in, const float* __restrict__ ws_out,
    short* __restrict__ wbf) {
  __shared__ float tP[64][65];
  __shared__ float tX[64][65];
  int b = blockIdx.x;
  int cb = b & 3;
  int h  = (b >> 2) & 63;
  int nt = b >> 8;
  int n = nt >> 1, t = nt & 1;
  int c0 = cb * 64;
  int bh = h >> 4, ii = h & 15;
  long inbase = (long)n * 2097152 + (long)t * 4096 + (long)h * 64;
  int tx = threadIdx.x & 63;
  int ty = threadIdx.x >> 6;  // 0..3

  for (int cc = ty; cc < 64; cc += 4) {
    long a = inbase + (long)(c0 + cc) * 8192 + tx;
    tP[cc][tx] = pos[a];
    tX[cc][tx] = q[a];
  }
  __syncthreads();
  for (int ww = ty; ww < 64; ww += 4) {
    int bw = ww >> 4, j = ww & 15;
    int m1 = (((t * 4 + bh) * 4 + bw) * 512) + n * 256 + ii * 16 + j;
    long o = (long)m1 * 256 + c0 + tx;
    float pv = tP[tx][ww];
    Xp[o] = f2bf(pv);
    Xq[o] = f2bf(tX[tx][ww] + pv);
  }
  __syncthreads();
  for (int cc = ty; cc < 64; cc += 4) {
    long a = inbase + (long)(c0 + cc) * 8192 + tx;
    tX[cc][tx] = k[a];
  }
  __syncthreads();
  for (int ww = ty; ww < 64; ww += 4) {
    int bw = ww >> 4, j = ww & 15;
    int m1 = (((t * 4 + bh) * 4 + bw) * 512) + n * 256 + ii * 16 + j;
    long o = (long)m1 * 256 + c0 + tx;
    Xk[o] = f2bf(tX[tx][ww] + tP[tx][ww]);
  }
  __syncthreads();
  for (int cc = ty; cc < 64; cc += 4) {
    long a = inbase + (long)(c0 + cc) * 8192 + tx;
    tX[cc][tx] = v[a];
  }
  __syncthreads();
  for (int ww = ty; ww < 64; ww += 4) {
    int bw = ww >> 4, j = ww & 15;
    int m1 = (((t * 4 + bh) * 4 + bw) * 512) + n * 256 + ii * 16 + j;
    long o = (long)m1 * 256 + c0 + tx;
    Xv[o] = f2bf(tX[tx][ww]);
  }
  // weight convert tail: 1024 blocks x 256 threads x 2 floats = 524288
  int idx = (blockIdx.x * 256 + threadIdx.x) * 2;
  const float* wp;
  if (idx < 196608) wp = wl_in + idx;
  else if (idx < 262144) wp = wl_out + (idx - 196608);
  else if (idx < 458752) wp = ws_in + (idx - 262144);
  else wp = ws_out + (idx - 458752);
  float2 wv = *(const float2*)wp;
  wbf[idx] = f2bf(wv.x);
  wbf[idx + 1] = f2bf(wv.y);
}

// ------- m97-style bf16 TN GEMM triple: C_z = A_z @ W_z^T + b_z -------------
// Tile 128x64, BK=64, global_load_lds 16B staging, XOR swizzle pc=c^(row&7).
template <bool OUT32>
__global__ __launch_bounds__(256) void gemm_tri(
    const short* __restrict__ A0, const short* __restrict__ A1,
    const short* __restrict__ A2, const short* __restrict__ W0,
    const float* __restrict__ bias0, void* __restrict__ C0,
    void* __restrict__ C1, void* __restrict__ C2) {
  __shared__ short As[128 * 64];  // 16 KB
  __shared__ short Ws[64 * 64];   //  8 KB
  int z = blockIdx.z;
  const short* A = (z == 0) ? A0 : ((z == 1) ? A1 : A2);
  const short* Wb = W0 + z * 65536;
  const float* bias = bias0 + z * 256;
  void* Csel = (z == 0) ? C0 : ((z == 1) ? C1 : C2);
  int m0 = blockIdx.x * 128;
  int n0 = blockIdx.y * 64;
  int tid = threadIdx.x;
  int lane = tid & 63, wave = tid >> 6;
  int wm = wave >> 1, wn = wave & 1;
  int l15 = lane & 15, quad = lane >> 4;
  int x7 = l15 & 7;
  int rsub = lane >> 3;   // 0..7: row within 8-row staging chunk
  int csub = lane & 7;    // logical col16 before swizzle

  floatx4 acc[4][2];
#pragma unroll
  for (int mt = 0; mt < 4; ++mt)
#pragma unroll
    for (int nt = 0; nt < 2; ++nt) acc[mt][nt] = (floatx4)(0.f);

  for (int kb = 0; kb < 4; ++kb) {
    int k0 = kb * 64;
    if (kb) __syncthreads();
#pragma unroll
    for (int j = 0; j < 4; ++j) {
      int r0 = (wave * 4 + j) * 8;
      int row = r0 + rsub;
      int c = csub ^ (row & 7);
      const short* gp = A + (long)(m0 + row) * 256 + k0 + c * 8;
      short* lp = &As[r0 * 64 + lane * 8];
      __builtin_amdgcn_global_load_lds((const GLOBAL_AS void*)gp,
                                       (LDS_AS void*)lp, 16, 0, 0);
    }
#pragma unroll
    for (int j = 0; j < 2; ++j) {
      int r0 = (wave * 2 + j) * 8;
      int row = r0 + rsub;
      int c = csub ^ (row & 7);
      const short* gp = Wb + (long)(n0 + row) * 256 + k0 + c * 8;
      short* lp = &Ws[r0 * 64 + lane * 8];
      __builtin_amdgcn_global_load_lds((const GLOBAL_AS void*)gp,
                                       (LDS_AS void*)lp, 16, 0, 0);
    }
    __syncthreads();
#pragma unroll
    for (int ks = 0; ks < 2; ++ks) {
      int pc = (ks * 4 + quad) ^ x7;
      short8 af[4], bfr[2];
#pragma unroll
      for (int mt = 0; mt < 4; ++mt) {
        int row = wm * 64 + mt * 16 + l15;
        af[mt] = *(const short8*)&As[row * 64 + pc * 8];
      }
#pragma unroll
      for (int nt = 0; nt < 2; ++nt) {
        int row = wn * 32 + nt * 16 + l15;
        bfr[nt] = *(const short8*)&Ws[row * 64 + pc * 8];
      }
#pragma unroll
      for (int mt = 0; mt < 4; ++mt)
#pragma unroll
        for (int nt = 0; nt < 2; ++nt)
          acc[mt][nt] = __builtin_amdgcn_mfma_f32_16x16x32_bf16(
              af[mt], bfr[nt], acc[mt][nt], 0, 0, 0);
    }
  }
  float bia0 = bias[n0 + wn * 32 + l15];
  float bia1 = bias[n0 + wn * 32 + 16 + l15];
#pragma unroll
  for (int mt = 0; mt < 4; ++mt) {
#pragma unroll
    for (int r = 0; r < 4; ++r) {
      int row = m0 + wm * 64 + mt * 16 + quad * 4 + r;
      long base = (long)row * 256 + n0 + wn * 32 + l15;
      if (OUT32) {
        float* C = (float*)Csel;
        C[base] = acc[mt][0][r] + bia0;
        C[base + 16] = acc[mt][1][r] + bia1;
      } else {
        short* C = (short*)Csel;
        C[base] = f2bf(acc[mt][0][r] + bia0);
        C[base + 16] = f2bf(acc[mt][1][r] + bia1);
      }
    }
  }
}

// ---- giga-fused stage-1: in-proj + attn + out-proj + perm + pos + s2-in-proj
// One block (4 waves) per b1. Regions: R1=Xq->Q1->O1s, R2=Xk->K1->X2s,
// R3=Xv->V1->Vins, R4 = Ws / (Vt+Pw). 80 KB -> 2 blk/CU.
__global__ __launch_bounds__(256) void attn1_giga(
    const short* __restrict__ Xq, const short* __restrict__ Xk,
    const short* __restrict__ Xv, const short* __restrict__ Xp,
    const short* __restrict__ Wlin, const float* __restrict__ bias_lin,
    const short* __restrict__ Wo, const float* __restrict__ bias_o,
    const short* __restrict__ Wsin, const float* __restrict__ bias_sin,
    short* __restrict__ Q2, short* __restrict__ K2, short* __restrict__ V2) {
  __shared__ short R1[32 * 256];   // 16 KB
  __shared__ short R2[32 * 256];   // 16 KB
  __shared__ short R3[32 * 256];   // 16 KB
  __shared__ short R4[256 * 64];   // 32 KB (Ws; or Vt+Pw during attn)
  int b1 = blockIdx.x;
  int tid = threadIdx.x;
  int wave = tid >> 6, lane = tid & 63;
  int l15 = lane & 15, quad = lane >> 4;
  int x7 = l15 & 7;
  int rsub = lane >> 3;
  int csub = lane & 7;

  floatx4 acc[2][4];

  // ======== phase A: Q1/K1/V1 = Xz @ wl_z^T + b_z, in place ========
#pragma unroll 1
  for (int z = 0; z < 3; ++z) {
    short* Rz = (z == 0) ? R1 : ((z == 1) ? R2 : R3);
    const short* Xg = (z == 0) ? Xq : ((z == 1) ? Xk : Xv);
    const short* Wz = Wlin + z * 65536;
    stage_tile(Rz, Xg, b1, tid);
#pragma unroll
    for (int mt = 0; mt < 2; ++mt)
#pragma unroll
      for (int nt = 0; nt < 4; ++nt) acc[mt][nt] = (floatx4)(0.f);
    for (int kb = 0; kb < 4; ++kb) {
      __syncthreads();   // prior Ws reads done; kb=0: tile DMA drained
      stage_w(R4, Wz, kb, wave, lane, rsub, csub);
      __syncthreads();
#pragma unroll
      for (int ks = 0; ks < 2; ++ks) {
        int pc = (ks * 4 + quad) ^ x7;
        short8 af[2], bfr[4];
#pragma unroll
        for (int mt = 0; mt < 2; ++mt)
          af[mt] = *(const short8*)&Rz[(mt * 16 + l15) * 256 + kb * 64 + pc * 8];
#pragma unroll
        for (int nt = 0; nt < 4; ++nt)
          bfr[nt] = *(const short8*)&R4[(wave * 64 + nt * 16 + l15) * 64 + pc * 8];
#pragma unroll
        for (int mt = 0; mt < 2; ++mt)
#pragma unroll
          for (int nt = 0; nt < 4; ++nt)
            acc[mt][nt] = __builtin_amdgcn_mfma_f32_16x16x32_bf16(
                af[mt], bfr[nt], acc[mt][nt], 0, 0, 0);
      }
    }
    __syncthreads();  // all waves done reading Rz before overwrite
    float bz[4];
#pragma unroll
    for (int nt = 0; nt < 4; ++nt)
      bz[nt] = bias_lin[z * 256 + wave * 64 + nt * 16 + l15];
#pragma unroll
    for (int mt = 0; mt < 2; ++mt)
#pragma unroll
      for (int r = 0; r < 4; ++r) {
        int row = mt * 16 + quad * 4 + r;
#pragma unroll
        for (int nt = 0; nt < 4; ++nt) {
          int col = wave * 64 + nt * 16 + l15;
          Rz[o1s_phys(row, col)] = f2bf(acc[mt][nt][r] + bz[nt]);
        }
      }
  }
  __syncthreads();  // Q1/K1/V1 tiles visible to all waves

  // ======== phase B: attention (frags from swizzled LDS) ========
  short* Vtb = R4;           // [4][32][40] shorts = 5120
  short* Pwb = R4 + 5120;    // [4][32][40]
  int key = lane & 31;
  int dh = (lane >> 5) * 16;                 // 0 or 16
  int pc2 = 2 * (key & 15) + (key >> 4);     // pi2(key)

  floatx4 oacc[2][4];    // [h2][o00,o01,o10,o11]
  float lsum[2][2][4];   // [h2][li0/li1][r]

#pragma unroll
  for (int h2 = 0; h2 < 2; ++h2) {
    int hh = wave * 2 + h2;
    int cb0 = hh * 32 + quad * 8;
    short8 qf0 = *(const short8*)&R1[o1s_phys(l15, cb0)];
    short8 qf1 = *(const short8*)&R1[o1s_phys(l15 + 16, cb0)];
    short8 kf0 = *(const short8*)&R2[o1s_phys(l15, cb0)];
    short8 kf1 = *(const short8*)&R2[o1s_phys(l15 + 16, cb0)];
    // V^T for this head: Vt[d][pi2(key)]; lanes 0-31: d 0..15, 32-63: 16..31
    short8 v0 = *(const short8*)&R3[o1s_phys(key, hh * 32 + dh)];
    short8 v1 = *(const short8*)&R3[o1s_phys(key, hh * 32 + dh + 8)];
#pragma unroll
    for (int j = 0; j < 8; ++j) {
      Vtb[(wave * 32 + dh + j) * 40 + pc2] = v0[j];
      Vtb[(wave * 32 + dh + 8 + j) * 40 + pc2] = v1[j];
    }
    // S = Q K^T (4 tiles)
    floatx4 s00 = __builtin_amdgcn_mfma_f32_16x16x32_bf16(qf0, kf0, (floatx4)(0.f), 0, 0, 0);
    floatx4 s01 = __builtin_amdgcn_mfma_f32_16x16x32_bf16(qf0, kf1, (floatx4)(0.f), 0, 0, 0);
    floatx4 s10 = __builtin_amdgcn_mfma_f32_16x16x32_bf16(qf1, kf0, (floatx4)(0.f), 0, 0, 0);
    floatx4 s11 = __builtin_amdgcn_mfma_f32_16x16x32_bf16(qf1, kf1, (floatx4)(0.f), 0, 0, 0);
    // no-max softmax; P[q][pi2(k)]: key tiles j=0,1 -> cols 2*l15, 2*l15+1
    float li0[4], li1[4];
#pragma unroll
    for (int r = 0; r < 4; ++r) {
      float p00 = __builtin_amdgcn_exp2f(s00[r] * EXP2_SCALE);
      float p01 = __builtin_amdgcn_exp2f(s01[r] * EXP2_SCALE);
      float p10 = __builtin_amdgcn_exp2f(s10[r] * EXP2_SCALE);
      float p11 = __builtin_amdgcn_exp2f(s11[r] * EXP2_SCALE);
      li0[r] = p00 + p01;
      li1[r] = p10 + p11;
      short2v pa, pb;
      pa.x = f2bf(p00); pa.y = f2bf(p01);
      pb.x = f2bf(p10); pb.y = f2bf(p11);
      *(short2v*)&Pwb[(wave * 32 + quad * 4 + r) * 40 + 2 * l15] = pa;
      *(short2v*)&Pwb[(wave * 32 + 16 + quad * 4 + r) * 40 + 2 * l15] = pb;
    }
#pragma unroll
    for (int r = 0; r < 4; ++r) {
      li0[r] += __shfl_xor(li0[r], 1, 64);
      li0[r] += __shfl_xor(li0[r], 2, 64);
      li0[r] += __shfl_xor(li0[r], 4, 64);
      li0[r] += __shfl_xor(li0[r], 8, 64);
      li1[r] += __shfl_xor(li1[r], 1, 64);
      li1[r] += __shfl_xor(li1[r], 2, 64);
      li1[r] += __shfl_xor(li1[r], 4, 64);
      li1[r] += __shfl_xor(li1[r], 8, 64);
      lsum[h2][0][r] = li0[r];
      lsum[h2][1][r] = li1[r];
    }
    // PV: O[32q][32d] = P[32q][32k] V[32k][32d] (k pi2-ordered both sides)
    short8 pf0 = *(const short8*)&Pwb[(wave * 32 + l15) * 40 + quad * 8];
    short8 pf1 = *(const short8*)&Pwb[(wave * 32 + 16 + l15) * 40 + quad * 8];
    short8 vt0 = *(const short8*)&Vtb[(wave * 32 + l15) * 40 + quad * 8];
    short8 vt1 = *(const short8*)&Vtb[(wave * 32 + 16 + l15) * 40 + quad * 8];
    oacc[h2][0] = __builtin_amdgcn_mfma_f32_16x16x32_bf16(pf0, vt0, (floatx4)(0.f), 0, 0, 0);
    oacc[h2][1] = __builtin_amdgcn_mfma_f32_16x16x32_bf16(pf0, vt1, (floatx4)(0.f), 0, 0, 0);
    oacc[h2][2] = __builtin_amdgcn_mfma_f32_16x16x32_bf16(pf1, vt0, (floatx4)(0.f), 0, 0, 0);
    oacc[h2][3] = __builtin_amdgcn_mfma_f32_16x16x32_bf16(pf1, vt1, (floatx4)(0.f), 0, 0, 0);
  }

  __syncthreads();  // attn LDS reads done; R4/R1 safe to overwrite

  // ---- issue Wo kb0 stage (into R4, overlays dead Vt/Pw), then spill ----
  stage_w(R4, Wo, 0, wave, lane, rsub, csub);
#pragma unroll
  for (int h2 = 0; h2 < 2; ++h2) {
    int hh = wave * 2 + h2;
    int cA = hh * 32 + l15;
    int cB = cA + 16;
#pragma unroll
    for (int r = 0; r < 4; ++r) {
      float inv0 = 1.f / lsum[h2][0][r];
      float inv1 = 1.f / lsum[h2][1][r];
      int qa = quad * 4 + r, qb = 16 + quad * 4 + r;
      R1[o1s_phys(qa, cA)] = f2bf(oacc[h2][0][r] * inv0);
      R1[o1s_phys(qa, cB)] = f2bf(oacc[h2][1][r] * inv0);
      R1[o1s_phys(qb, cA)] = f2bf(oacc[h2][2][r] * inv1);
      R1[o1s_phys(qb, cB)] = f2bf(oacc[h2][3][r] * inv1);
    }
  }
  __syncthreads();  // Wo kb0 staged + O1s spill visible

  // ======== phase C: C1 = O1s @ Wo^T ========
#pragma unroll
  for (int mt = 0; mt < 2; ++mt)
#pragma unroll
    for (int nt = 0; nt < 4; ++nt) acc[mt][nt] = (floatx4)(0.f);
  for (int kb = 0; kb < 4; ++kb) {
    if (kb) {
      __syncthreads();
      stage_w(R4, Wo, kb, wave, lane, rsub, csub);
      __syncthreads();
    }
#pragma unroll
    for (int ks = 0; ks < 2; ++ks) {
      int pc = (ks * 4 + quad) ^ x7;
      short8 af[2], bfr[4];
#pragma unroll
      for (int mt = 0; mt < 2; ++mt)
        af[mt] = *(const short8*)&R1[(mt * 16 + l15) * 256 + kb * 64 + pc * 8];
#pragma unroll
      for (int nt = 0; nt < 4; ++nt)
        bfr[nt] = *(const short8*)&R4[(wave * 64 + nt * 16 + l15) * 64 + pc * 8];
#pragma unroll
      for (int mt = 0; mt < 2; ++mt)
#pragma unroll
        for (int nt = 0; nt < 4; ++nt)
          acc[mt][nt] = __builtin_amdgcn_mfma_f32_16x16x32_bf16(
              af[mt], bfr[nt], acc[mt][nt], 0, 0, 0);
    }
  }

  __syncthreads();
  // ---- X2s (=C1+b+pos) -> R2, Vins (=C1+b) -> R3, both swizzled ----
  {
    float bvo[4];
#pragma unroll
    for (int nt = 0; nt < 4; ++nt) bvo[nt] = bias_o[wave * 64 + nt * 16 + l15];
#pragma unroll
    for (int mt = 0; mt < 2; ++mt) {
#pragma unroll
      for (int r = 0; r < 4; ++r) {
        int qrow = mt * 16 + quad * 4 + r;
        long pbase = ((long)qrow * 512 + b1) * 256;
#pragma unroll
        for (int nt = 0; nt < 4; ++nt) {
          int col = wave * 64 + nt * 16 + l15;
          float val = acc[mt][nt][r] + bvo[nt];
          int ph = o1s_phys(qrow, col);
          R3[ph] = f2bf(val);
          R2[ph] = f2bf(val + bf2f(Xp[pbase + col]));  // X2s
        }
      }
    }
  }

  // ======== phase D: Q2/K2/V2 = {X2s,X2s,Vins} @ ws_{q,k,v}^T + b ========
  int nn = b1 >> 8, ii = (b1 >> 4) & 15, jj = b1 & 15;
#pragma unroll 1
  for (int z = 0; z < 3; ++z) {
    const short* Wz = Wsin + z * 65536;
    const short* Ab = (z < 2) ? R2 : R3;
    short* outz = (z == 0) ? Q2 : ((z == 1) ? K2 : V2);
    float bz[4];
#pragma unroll
    for (int nt = 0; nt < 4; ++nt)
      bz[nt] = bias_sin[z * 256 + wave * 64 + nt * 16 + l15];
#pragma unroll
    for (int mt = 0; mt < 2; ++mt)
#pragma unroll
      for (int nt = 0; nt < 4; ++nt) acc[mt][nt] = (floatx4)(0.f);
    for (int kb = 0; kb < 4; ++kb) {
      __syncthreads();  // z0/kb0: X2s/Vins visible; else prior Ws reads done
      stage_w(R4, Wz, kb, wave, lane, rsub, csub);
      __syncthreads();
#pragma unroll
      for (int ks = 0; ks < 2; ++ks) {
        int pc = (ks * 4 + quad) ^ x7;
        short8 af[2], bfr[4];
#pragma unroll
        for (int mt = 0; mt < 2; ++mt)
          af[mt] = *(const short8*)&Ab[(mt * 16 + l15) * 256 + kb * 64 + pc * 8];
#pragma unroll
        for (int nt = 0; nt < 4; ++nt)
          bfr[nt] = *(const short8*)&R4[(wave * 64 + nt * 16 + l15) * 64 + pc * 8];
#pragma unroll
        for (int mt = 0; mt < 2; ++mt)
#pragma unroll
          for (int nt = 0; nt < 4; ++nt)
            acc[mt][nt] = __builtin_amdgcn_mfma_f32_16x16x32_bf16(
                af[mt], bfr[nt], acc[mt][nt], 0, 0, 0);
      }
    }
    // epilogue: +bias, m1->m2 perm, store
#pragma unroll
    for (int mt = 0; mt < 2; ++mt) {
#pragma unroll
      for (int r = 0; r < 4; ++r) {
        int qrow = mt * 16 + quad * 4 + r;
        int t = qrow >> 4, bh = (qrow >> 2) & 3, bw = qrow & 3;
        int m2 = (t * 256 + ii * 16 + jj) * 32 + nn * 16 + bh * 4 + bw;
        long xbase = (long)m2 * 256;
#pragma unroll
        for (int nt = 0; nt < 4; ++nt) {
          int col = wave * 64 + nt * 16 + l15;
          outz[xbase + col] = f2bf(acc[mt][nt][r] + bz[nt]);
        }
      }
    }
  }
}

// ---------------- stage-2 attention: MFMA flash, no-max softmax -------------
// R6 staging (LDS K + pi-V^T, 2 barriers/chunk) + exp2 no-max softmax.
// grid 2048: bid = qblk*256 + rest, rest = (hh&1)*128 + b2*4 + (hh>>1).
__global__ __launch_bounds__(256) void attn2_mfma(
    const short* __restrict__ Q2, const short* __restrict__ K2,
    const short* __restrict__ V2, short* __restrict__ O2) {
  __shared__ short Ks[64][40];      // [key][d]
  __shared__ short Vt[32][72];      // [d][pi(key)]
  __shared__ short Pw[4][16][72];   // per-wave P [q][pi(key)]
  int bid = blockIdx.x;
  int rest = bid & 255;
  int qblk = bid >> 8;
  int hh = 2 * (rest & 3) + (rest >> 7);
  int b2 = (rest >> 2) & 31;
  int tid = threadIdx.x;
  int wave = tid >> 6, lane = tid & 63;
  int l15 = lane & 15, quad = lane >> 4;

  short8 qf;
  {
    long tok = (long)(qblk * 64 + wave * 16 + l15) * 32 + b2;
    qf = *(const short8*)(Q2 + tok * 256 + hh * 32 + quad * 8);
  }
  floatx4 Oa = (floatx4)(0.f), Ob = (floatx4)(0.f);
  float li[4] = {0.f, 0.f, 0.f, 0.f};

  int skey = tid >> 2;          // K staging: 0..63
  int sd0 = (tid & 3) * 8;
  int vkey = lane;              // V staging
  int vd0 = wave * 8;
  int vcol = (vkey & 15) * 4 + (vkey >> 4);  // pi(key)

  for (int kb = 0; kb < 8; ++kb) {
    if (kb) __syncthreads();
    {  // stage K [64][32] bf16 passthrough
      long tok = (long)(kb * 64 + skey) * 32 + b2;
      *(short8*)&Ks[skey][sd0] = *(const short8*)(K2 + tok * 256 + hh * 32 + sd0);
    }
    {  // stage V^T [32][pi(64)] bf16 passthrough
      long tok = (long)(kb * 64 + vkey) * 32 + b2;
      short8 v = *(const short8*)(V2 + tok * 256 + hh * 32 + vd0);
#pragma unroll
      for (int j = 0; j < 8; ++j) Vt[vd0 + j][vcol] = v[j];
    }
    __syncthreads();
    floatx4 st[4];
#pragma unroll
    for (int kt = 0; kt < 4; ++kt) {
      short8 kf = *(const short8*)&Ks[kt * 16 + l15][quad * 8];
      st[kt] = __builtin_amdgcn_mfma_f32_16x16x32_bf16(qf, kf, (floatx4)(0.f), 0, 0, 0);
    }
#pragma unroll
    for (int r = 0; r < 4; ++r) {
      float p0 = __builtin_amdgcn_exp2f(st[0][r] * EXP2_SCALE);
      float p1 = __builtin_amdgcn_exp2f(st[1][r] * EXP2_SCALE);
      float p2 = __builtin_amdgcn_exp2f(st[2][r] * EXP2_SCALE);
      float p3 = __builtin_amdgcn_exp2f(st[3][r] * EXP2_SCALE);
      li[r] += (p0 + p1) + (p2 + p3);
      short4v pp;
      pp.x = f2bf(p0); pp.y = f2bf(p1); pp.z = f2bf(p2); pp.w = f2bf(p3);
      *(short4v*)&Pw[wave][quad * 4 + r][l15 * 4] = pp;
    }
#pragma unroll
    for (int kk = 0; kk < 2; ++kk) {
      short8 pf = *(const short8*)&Pw[wave][l15][kk * 32 + quad * 8];
      short8 v0 = *(const short8*)&Vt[l15][kk * 32 + quad * 8];
      short8 v1 = *(const short8*)&Vt[16 + l15][kk * 32 + quad * 8];
      Oa = __builtin_amdgcn_mfma_f32_16x16x32_bf16(pf, v0, Oa, 0, 0, 0);
      Ob = __builtin_amdgcn_mfma_f32_16x16x32_bf16(pf, v1, Ob, 0, 0, 0);
    }
  }
#pragma unroll
  for (int r = 0; r < 4; ++r) {
    float s = li[r];
    s += __shfl_xor(s, 1, 64);
    s += __shfl_xor(s, 2, 64);
    s += __shfl_xor(s, 4, 64);
    s += __shfl_xor(s, 8, 64);
    float inv = 1.f / s;
    long tok = (long)(qblk * 64 + wave * 16 + quad * 4 + r) * 32 + b2;
    long a = tok * 256 + hh * 32 + l15;
    O2[a] = f2bf(Oa[r] * inv);
    O2[a + 16] = f2bf(Ob[r] * inv);
  }
}

// ---------------- unpack: [16384,256] fp32 (m2-order) -> out [n,c,t,h,w] ----
__global__ __launch_bounds__(256) void unpack_kernel(
    const float* __restrict__ Y, float* __restrict__ out) {
  __shared__ float tl[64][65];
  int b = blockIdx.x;
  int cb = b & 3;
  int h = (b >> 2) & 63;
  int nt = b >> 8;
  int n = nt >> 1, t = nt & 1;
  int c0 = cb * 64;
  int bh = h >> 4, ii = h & 15;
  int tx = threadIdx.x & 63;
  int ty = threadIdx.x >> 6;
  for (int ww = ty; ww < 64; ww += 4) {
    int bw = ww >> 4, j = ww & 15;
    int l2 = t * 256 + ii * 16 + j;
    int b2 = n * 16 + bh * 4 + bw;
    int m2 = l2 * 32 + b2;
    tl[tx][ww] = Y[(long)m2 * 256 + c0 + tx];
  }
  __syncthreads();
  long ob = (long)n * 2097152 + (long)t * 4096 + (long)h * 64 + tx;
  for (int cc = ty; cc < 64; cc += 4) {
    out[ob + (long)(c0 + cc) * 8192] = tl[cc][tx];
  }
}

extern "C" void kernel_launch(void* const* d_in, const int* in_sizes, int n_in,
                              void* d_out, int out_size, void* d_ws, size_t ws_size,
                              hipStream_t stream) {
  const float* q      = (const float*)d_in[0];
  const float* k      = (const float*)d_in[1];
  const float* v      = (const float*)d_in[2];
  const float* pos    = (const float*)d_in[3];
  const float* wl_in  = (const float*)d_in[4];
  const float* bl_in  = (const float*)d_in[5];
  const float* wl_out = (const float*)d_in[6];
  const float* bl_out = (const float*)d_in[7];
  const float* ws_in  = (const float*)d_in[8];
  const float* bs_in  = (const float*)d_in[9];
  const float* ws_out = (const float*)d_in[10];
  const float* bs_out = (const float*)d_in[11];
  float* out = (float*)d_out;
  char* wsb = (char*)d_ws;
  const size_t SLB = 16777216;  // 16 MB per slot (bf16 tensors use half)
  short* s0 = (short*)(wsb);            // Xp (8 MB)
  short* wbf = (short*)(wsb + SLB / 2); // bf16 weights (1 MB)
  short* s1 = (short*)(wsb + SLB);      // Xq -> O2
  short* s2 = (short*)(wsb + 2 * SLB);  // Xk -> Yfinal(fp32)
  short* s3 = (short*)(wsb + 3 * SLB);  // Xv
  short* s4 = (short*)(wsb + 4 * SLB);  // Q2
  short* s5 = (short*)(wsb + 5 * SLB);  // K2
  short* s6 = (short*)(wsb + 6 * SLB);  // V2

  pack_kernel<<<1024, 256, 0, stream>>>(q, k, v, pos, s0, s1, s2, s3,
                                        wl_in, wl_out, ws_in, ws_out, wbf);

  // giga-fused stage-1 (in-proj + attn + out-proj + perm + pos + s2 in-proj):
  // Q2 -> s4, K2 -> s5, V2 -> s6
  attn1_giga<<<512, 256, 0, stream>>>(s1, s2, s3, s0, wbf, bl_in,
                                      wbf + 196608, bl_out,
                                      wbf + 262144, bs_in, s4, s5, s6);

  attn2_mfma<<<2048, 256, 0, stream>>>(s4, s5, s6, s1);   // O2 -> s1
  // Yfinal (fp32) = O2 @ ws_out^T
  dim3 g1(128, 4, 1);
  gemm_tri<true><<<g1, 256, 0, stream>>>(s1, s1, s1, wbf + 458752, bs_out,
                                         s2, s2, s2);

  unpack_kernel<<<1024, 256, 0, stream>>>((const float*)s2, out);
}